// Round 2
// baseline (282.255 us; speedup 1.0000x reference)
//
#include <hip/hip_runtime.h>

typedef __attribute__((ext_vector_type(8))) short bf16x8;
typedef __attribute__((ext_vector_type(4))) short bf16x4;
typedef __attribute__((ext_vector_type(4))) float f32x4;

#define MFMA(a, b, c) __builtin_amdgcn_mfma_f32_16x16x32_bf16((a), (b), (c), 0, 0, 0)

__device__ __forceinline__ unsigned short f2bf(float f) {
  unsigned int x = __float_as_uint(f);
  return (unsigned short)((x + 0x7fffu + ((x >> 16) & 1u)) >> 16);
}

constexpr int SEQ = 2048;
constexpr int NH = 8;
constexpr int DH = 128;
constexpr int DIM = 1024;
constexpr float SCALE = 0.08838834764831845f; // 1/sqrt(128)

// ---------------------------------------------------------------------------
// K1: qkv = x @ qkv_proj^T  (M=4096, N=3072, K=1024), fused RoPE epilogue.
// Writes q,k as (B,H,T,DH) bf16, v transposed as (B,H,DH,T) bf16.
// ---------------------------------------------------------------------------
__global__ __launch_bounds__(256) void k_qkv_rope(
    const float* __restrict__ x, const float* __restrict__ wqkv,
    const float* __restrict__ cosT, const float* __restrict__ sinT,
    unsigned short* __restrict__ q, unsigned short* __restrict__ k,
    unsigned short* __restrict__ vT)
{
  __shared__ __align__(16) unsigned short As[128][40]; // pitch 40 bf16 = 80B
  __shared__ __align__(16) unsigned short Bs[128][40];
  const int tid = threadIdx.x;
  const int wave = tid >> 6, lane = tid & 63;
  const int fr = lane & 15, fq = lane >> 4;
  const int fk = fq * 8;
  const int wr = (wave >> 1) * 64, wc = (wave & 1) * 64;
  const int m0 = blockIdx.x * 128, n0 = blockIdx.y * 128;

  f32x4 zero4 = {0.f, 0.f, 0.f, 0.f};
  f32x4 acc[4][4];
  for (int i = 0; i < 4; ++i)
    for (int j = 0; j < 4; ++j) acc[i][j] = zero4;

  for (int kt = 0; kt < 32; ++kt) {
    const int k0 = kt * 32;
    __syncthreads();
#pragma unroll
    for (int j = 0; j < 4; ++j) {
      int f = j * 256 + tid;
      int row = f >> 3, c4 = (f & 7) * 4;
      f32x4 va = *(const f32x4*)(x + (m0 + row) * 1024 + k0 + c4);
      f32x4 vb = *(const f32x4*)(wqkv + (n0 + row) * 1024 + k0 + c4);
      bf16x4 ha, hb;
#pragma unroll
      for (int e = 0; e < 4; ++e) {
        ha[e] = (short)f2bf(va[e]);
        hb[e] = (short)f2bf(vb[e]);
      }
      *(bf16x4*)&As[row][c4] = ha;
      *(bf16x4*)&Bs[row][c4] = hb;
    }
    __syncthreads();
    bf16x8 af[4], bfr[4];
#pragma unroll
    for (int mi = 0; mi < 4; ++mi) af[mi] = *(const bf16x8*)&As[wr + mi * 16 + fr][fk];
#pragma unroll
    for (int ni = 0; ni < 4; ++ni) bfr[ni] = *(const bf16x8*)&Bs[wc + ni * 16 + fr][fk];
#pragma unroll
    for (int mi = 0; mi < 4; ++mi)
#pragma unroll
      for (int ni = 0; ni < 4; ++ni)
        acc[mi][ni] = MFMA(af[mi], bfr[ni], acc[mi][ni]);
  }

  // epilogue: D layout col=lane&15, row=(lane>>4)*4+r. Feature pairs (2i,2i+1)
  // sit in lanes (l, l^1) at the same row -> RoPE via shfl_xor(1).
#pragma unroll
  for (int mi = 0; mi < 4; ++mi)
#pragma unroll
    for (int ni = 0; ni < 4; ++ni)
#pragma unroll
      for (int r = 0; r < 4; ++r) {
        float val = acc[mi][ni][r];
        float other = __shfl_xor(val, 1, 64);
        int m = m0 + wr + mi * 16 + fq * 4 + r;
        int n = n0 + wc + ni * 16 + fr;
        int a = n >> 10, feat = n & 1023;
        int hh = feat >> 7, dh = feat & 127;
        int bi = m >> 11, t = m & 2047;
        if (a == 2) {
          vT[((bi * NH + hh) * DH + dh) * SEQ + t] = f2bf(val);
        } else {
          float c = cosT[t * 64 + (dh >> 1)];
          float s = sinT[t * 64 + (dh >> 1)];
          float o = ((dh & 1) == 0) ? (val * c - other * s) : (other * s + val * c);
          unsigned short* dst = (a == 0) ? q : k;
          dst[((bi * NH + hh) * SEQ + t) * DH + dh] = f2bf(o);
        }
      }
}

// ---------------------------------------------------------------------------
// K2: causal attention per (b, head, 64-row tile). Pass A: rowsums of exp.
// Pass B: recompute S, write normalized f32 attn + bf16 P (LDS transpose)
// for PV accumulation.
// ---------------------------------------------------------------------------
__global__ __launch_bounds__(256) void k_attn(
    const unsigned short* __restrict__ q, const unsigned short* __restrict__ k,
    const unsigned short* __restrict__ vT,
    float* __restrict__ attn, unsigned short* __restrict__ heads)
{
  __shared__ __align__(16) unsigned short Kt[32][136];    // pitch 272B
  __shared__ __align__(16) unsigned short Vt[128][40];
  __shared__ __align__(16) unsigned short Esc[4][16][40]; // per-wave P transpose

  const int tid = threadIdx.x;
  const int wave = tid >> 6, lane = tid & 63;
  const int fr = lane & 15, fq = lane >> 4;
  const int fk = fq * 8;
  // balance causal work: pair row-tile x (b=0) with 31-x (b=1)
  const int rt = (blockIdx.z == 0) ? (int)blockIdx.x : (31 - (int)blockIdx.x);
  const int row0 = rt * 64;
  const int hh = blockIdx.y, bi = blockIdx.z;
  const int bh = bi * NH + hh;
  const int r0 = row0 + wave * 16;

  const unsigned short* qb = q + bh * SEQ * DH;
  const unsigned short* kb = k + bh * SEQ * DH;
  const unsigned short* vb = vT + bh * DH * SEQ;

  bf16x8 aq[4];
#pragma unroll
  for (int ks = 0; ks < 4; ++ks)
    aq[ks] = *(const bf16x8*)(qb + (r0 + fr) * DH + ks * 32 + fk);

  const int ntile = row0 / 32 + 2;
  const int wmax = r0 + 15;

  float rs[4] = {0.f, 0.f, 0.f, 0.f};

  // ---- pass A: row sums ----
  for (int nt = 0; nt < ntile; ++nt) {
    const int c0 = nt * 32;
    __syncthreads();
#pragma unroll
    for (int j = 0; j < 2; ++j) {
      int f = j * 256 + tid;
      int r = f >> 4, c = (f & 15) * 8;
      *(bf16x8*)&Kt[r][c] = *(const bf16x8*)(kb + (c0 + r) * DH + c);
    }
    __syncthreads();
    if (c0 <= wmax) {
#pragma unroll
      for (int half = 0; half < 2; ++half) {
        f32x4 s = {0.f, 0.f, 0.f, 0.f};
#pragma unroll
        for (int ks = 0; ks < 4; ++ks) {
          bf16x8 bk = *(const bf16x8*)&Kt[half * 16 + fr][ks * 32 + fk];
          s = MFMA(aq[ks], bk, s);
        }
        int col = c0 + half * 16 + fr;
#pragma unroll
        for (int r = 0; r < 4; ++r) {
          int row = r0 + fq * 4 + r;
          if (col <= row) rs[r] += __expf(s[r] * SCALE);
        }
      }
    }
  }

#pragma unroll
  for (int r = 0; r < 4; ++r)
#pragma unroll
    for (int msk = 1; msk < 16; msk <<= 1)
      rs[r] += __shfl_xor(rs[r], msk, 64);

  float inv[4];
#pragma unroll
  for (int r = 0; r < 4; ++r) inv[r] = 1.0f / rs[r];

  f32x4 pv[8];
  {
    f32x4 zero4 = {0.f, 0.f, 0.f, 0.f};
#pragma unroll
    for (int i = 0; i < 8; ++i) pv[i] = zero4;
  }

  // ---- pass B: normalized attn write (f32) + PV ----
  for (int nt = 0; nt < ntile; ++nt) {
    const int c0 = nt * 32;
    __syncthreads();
#pragma unroll
    for (int j = 0; j < 2; ++j) {
      int f = j * 256 + tid;
      int r = f >> 4, c = (f & 15) * 8;
      *(bf16x8*)&Kt[r][c] = *(const bf16x8*)(kb + (c0 + r) * DH + c);
      int rv = f >> 2, cv = (f & 3) * 8;
      *(bf16x8*)&Vt[rv][cv] = *(const bf16x8*)(vb + rv * SEQ + c0 + cv);
    }
    __syncthreads();
    if (c0 <= wmax) {
#pragma unroll
      for (int half = 0; half < 2; ++half) {
        f32x4 s = {0.f, 0.f, 0.f, 0.f};
#pragma unroll
        for (int ks = 0; ks < 4; ++ks) {
          bf16x8 bk = *(const bf16x8*)&Kt[half * 16 + fr][ks * 32 + fk];
          s = MFMA(aq[ks], bk, s);
        }
        int col = c0 + half * 16 + fr;
#pragma unroll
        for (int r = 0; r < 4; ++r) {
          int row = r0 + fq * 4 + r;
          float p = (col <= row) ? __expf(s[r] * SCALE) * inv[r] : 0.f;
          attn[((size_t)bh * SEQ + row) * SEQ + col] = p;      // f32 output
          Esc[wave][fq * 4 + r][half * 16 + fr] = f2bf(p);     // PV fragment
        }
      }
      bf16x8 ae = *(const bf16x8*)&Esc[wave][fr][fk];
#pragma unroll
      for (int ni = 0; ni < 8; ++ni) {
        bf16x8 bv = *(const bf16x8*)&Vt[ni * 16 + fr][fk];
        pv[ni] = MFMA(ae, bv, pv[ni]);
      }
    }
  }

#pragma unroll
  for (int ni = 0; ni < 8; ++ni)
#pragma unroll
    for (int r = 0; r < 4; ++r) {
      int row = r0 + fq * 4 + r;
      int dh = ni * 16 + fr;
      heads[(bi * SEQ + row) * DIM + hh * DH + dh] = f2bf(pv[ni][r]);
    }
}

// ---------------------------------------------------------------------------
// K3: out = heads @ w_out^T  (M=4096, N=1024, K=1024), f32 output
// ---------------------------------------------------------------------------
__global__ __launch_bounds__(256) void k_outproj(
    const unsigned short* __restrict__ heads, const float* __restrict__ wout,
    float* __restrict__ out)
{
  __shared__ __align__(16) unsigned short As[128][40];
  __shared__ __align__(16) unsigned short Bs[128][40];
  const int tid = threadIdx.x;
  const int wave = tid >> 6, lane = tid & 63;
  const int fr = lane & 15, fq = lane >> 4;
  const int fk = fq * 8;
  const int wr = (wave >> 1) * 64, wc = (wave & 1) * 64;
  const int m0 = blockIdx.x * 128, n0 = blockIdx.y * 128;

  f32x4 zero4 = {0.f, 0.f, 0.f, 0.f};
  f32x4 acc[4][4];
  for (int i = 0; i < 4; ++i)
    for (int j = 0; j < 4; ++j) acc[i][j] = zero4;

  for (int kt = 0; kt < 32; ++kt) {
    const int k0 = kt * 32;
    __syncthreads();
#pragma unroll
    for (int j = 0; j < 2; ++j) { // A tile: 128x32 bf16
      int f = j * 256 + tid;
      int row = f >> 2, c = (f & 3) * 8;
      *(bf16x8*)&As[row][c] = *(const bf16x8*)(heads + (m0 + row) * 1024 + k0 + c);
    }
#pragma unroll
    for (int j = 0; j < 4; ++j) { // B tile: 128x32 f32 -> bf16
      int f = j * 256 + tid;
      int row = f >> 3, c4 = (f & 7) * 4;
      f32x4 vb = *(const f32x4*)(wout + (n0 + row) * 1024 + k0 + c4);
      bf16x4 hb;
#pragma unroll
      for (int e = 0; e < 4; ++e) hb[e] = (short)f2bf(vb[e]);
      *(bf16x4*)&Bs[row][c4] = hb;
    }
    __syncthreads();
    bf16x8 af[4], bfr[4];
#pragma unroll
    for (int mi = 0; mi < 4; ++mi) af[mi] = *(const bf16x8*)&As[wr + mi * 16 + fr][fk];
#pragma unroll
    for (int ni = 0; ni < 4; ++ni) bfr[ni] = *(const bf16x8*)&Bs[wc + ni * 16 + fr][fk];
#pragma unroll
    for (int mi = 0; mi < 4; ++mi)
#pragma unroll
      for (int ni = 0; ni < 4; ++ni)
        acc[mi][ni] = MFMA(af[mi], bfr[ni], acc[mi][ni]);
  }

#pragma unroll
  for (int mi = 0; mi < 4; ++mi)
#pragma unroll
    for (int ni = 0; ni < 4; ++ni)
#pragma unroll
      for (int r = 0; r < 4; ++r) {
        int m = m0 + wr + mi * 16 + fq * 4 + r;
        int n = n0 + wc + ni * 16 + fr;
        out[m * 1024 + n] = acc[mi][ni][r];
      }
}

extern "C" void kernel_launch(void* const* d_in, const int* in_sizes, int n_in,
                              void* d_out, int out_size, void* d_ws, size_t ws_size,
                              hipStream_t stream)
{
  const float* x    = (const float*)d_in[0];
  const float* wqkv = (const float*)d_in[1];
  const float* wout = (const float*)d_in[2];
  const float* cosT = (const float*)d_in[3];
  const float* sinT = (const float*)d_in[4];

  float* out  = (float*)d_out;
  float* attn = out + 4194304; // B*T*DIM f32 elements, then attn f32
  unsigned short* ws   = (unsigned short*)d_ws;
  unsigned short* q     = ws;             // (B,H,T,DH) bf16
  unsigned short* kk    = ws + 4194304;   // (B,H,T,DH) bf16
  unsigned short* vT    = ws + 8388608;   // (B,H,DH,T) bf16
  unsigned short* heads = ws + 12582912;  // (B,T,DIM) bf16

  // zero attn (covers strict upper triangle); K2 fills the causal part
  hipMemsetAsync(attn, 0, (size_t)67108864 * 4, stream);
  k_qkv_rope<<<dim3(32, 24), 256, 0, stream>>>(x, wqkv, cosT, sinT, q, kk, vT);
  k_attn<<<dim3(32, 8, 2), 256, 0, stream>>>(q, kk, vT, attn, heads);
  k_outproj<<<dim3(32, 8), 256, 0, stream>>>(heads, wout, out);
}

// Round 3
// 241.779 us; speedup vs baseline: 1.1674x; 1.1674x over previous
//
#include <hip/hip_runtime.h>

typedef __attribute__((ext_vector_type(8))) short bf16x8;
typedef __attribute__((ext_vector_type(4))) short bf16x4;
typedef __attribute__((ext_vector_type(4))) float f32x4;

#define MFMA(a, b, c) __builtin_amdgcn_mfma_f32_16x16x32_bf16((a), (b), (c), 0, 0, 0)

__device__ __forceinline__ unsigned short f2bf(float f) {
  unsigned int x = __float_as_uint(f);
  return (unsigned short)((x + 0x7fffu + ((x >> 16) & 1u)) >> 16);
}

constexpr int SEQ = 2048;
constexpr int NH = 8;
constexpr int DH = 128;
constexpr int DIM = 1024;
constexpr float SCALE = 0.08838834764831845f; // 1/sqrt(128)

// ---------------------------------------------------------------------------
// K1: qkv = x @ qkv_proj^T  (M=4096, N=3072, K=1024), fused RoPE epilogue.
// Writes q,k as (B,H,T,DH) bf16, v transposed as (B,H,DH,T) bf16.
// ---------------------------------------------------------------------------
__global__ __launch_bounds__(256) void k_qkv_rope(
    const float* __restrict__ x, const float* __restrict__ wqkv,
    const float* __restrict__ cosT, const float* __restrict__ sinT,
    unsigned short* __restrict__ q, unsigned short* __restrict__ k,
    unsigned short* __restrict__ vT)
{
  __shared__ __align__(16) unsigned short As[128][40]; // pitch 40 bf16 = 80B
  __shared__ __align__(16) unsigned short Bs[128][40];
  const int tid = threadIdx.x;
  const int wave = tid >> 6, lane = tid & 63;
  const int fr = lane & 15, fq = lane >> 4;
  const int fk = fq * 8;
  const int wr = (wave >> 1) * 64, wc = (wave & 1) * 64;
  const int m0 = blockIdx.x * 128, n0 = blockIdx.y * 128;

  f32x4 zero4 = {0.f, 0.f, 0.f, 0.f};
  f32x4 acc[4][4];
  for (int i = 0; i < 4; ++i)
    for (int j = 0; j < 4; ++j) acc[i][j] = zero4;

  for (int kt = 0; kt < 32; ++kt) {
    const int k0 = kt * 32;
    __syncthreads();
#pragma unroll
    for (int j = 0; j < 4; ++j) {
      int f = j * 256 + tid;
      int row = f >> 3, c4 = (f & 7) * 4;
      f32x4 va = *(const f32x4*)(x + (m0 + row) * 1024 + k0 + c4);
      f32x4 vb = *(const f32x4*)(wqkv + (n0 + row) * 1024 + k0 + c4);
      bf16x4 ha, hb;
#pragma unroll
      for (int e = 0; e < 4; ++e) {
        ha[e] = (short)f2bf(va[e]);
        hb[e] = (short)f2bf(vb[e]);
      }
      *(bf16x4*)&As[row][c4] = ha;
      *(bf16x4*)&Bs[row][c4] = hb;
    }
    __syncthreads();
    bf16x8 af[4], bfr[4];
#pragma unroll
    for (int mi = 0; mi < 4; ++mi) af[mi] = *(const bf16x8*)&As[wr + mi * 16 + fr][fk];
#pragma unroll
    for (int ni = 0; ni < 4; ++ni) bfr[ni] = *(const bf16x8*)&Bs[wc + ni * 16 + fr][fk];
#pragma unroll
    for (int mi = 0; mi < 4; ++mi)
#pragma unroll
      for (int ni = 0; ni < 4; ++ni)
        acc[mi][ni] = MFMA(af[mi], bfr[ni], acc[mi][ni]);
  }

  // epilogue: D layout col=lane&15, row=(lane>>4)*4+r. Feature pairs (2i,2i+1)
  // sit in lanes (l, l^1) at the same row -> RoPE via shfl_xor(1).
#pragma unroll
  for (int mi = 0; mi < 4; ++mi)
#pragma unroll
    for (int ni = 0; ni < 4; ++ni)
#pragma unroll
      for (int r = 0; r < 4; ++r) {
        float val = acc[mi][ni][r];
        float other = __shfl_xor(val, 1, 64);
        int m = m0 + wr + mi * 16 + fq * 4 + r;
        int n = n0 + wc + ni * 16 + fr;
        int a = n >> 10, feat = n & 1023;
        int hh = feat >> 7, dh = feat & 127;
        int bi = m >> 11, t = m & 2047;
        if (a == 2) {
          vT[((bi * NH + hh) * DH + dh) * SEQ + t] = f2bf(val);
        } else {
          float c = cosT[t * 64 + (dh >> 1)];
          float s = sinT[t * 64 + (dh >> 1)];
          float o = ((dh & 1) == 0) ? (val * c - other * s) : (other * s + val * c);
          unsigned short* dst = (a == 0) ? q : k;
          dst[((bi * NH + hh) * SEQ + t) * DH + dh] = f2bf(o);
        }
      }
}

// ---------------------------------------------------------------------------
// K2: causal attention per (b, head, 64-row tile). Pass A: rowsums of exp.
// Pass B: recompute S, write normalized f32 attn + bf16 P (LDS transpose)
// for PV accumulation. Tail: vectorized zero-fill of the untouched
// upper-triangle region (replaces the 268MB memset).
// ---------------------------------------------------------------------------
__global__ __launch_bounds__(256) void k_attn(
    const unsigned short* __restrict__ q, const unsigned short* __restrict__ k,
    const unsigned short* __restrict__ vT,
    float* __restrict__ attn, unsigned short* __restrict__ heads)
{
  __shared__ __align__(16) unsigned short Kt[32][136];    // pitch 272B
  __shared__ __align__(16) unsigned short Vt[128][40];
  __shared__ __align__(16) unsigned short Esc[4][16][40]; // per-wave P transpose

  const int tid = threadIdx.x;
  const int wave = tid >> 6, lane = tid & 63;
  const int fr = lane & 15, fq = lane >> 4;
  const int fk = fq * 8;
  const int rt = (blockIdx.z == 0) ? (int)blockIdx.x : (31 - (int)blockIdx.x);
  const int row0 = rt * 64;
  const int hh = blockIdx.y, bi = blockIdx.z;
  const int bh = bi * NH + hh;
  const int r0 = row0 + wave * 16;

  const unsigned short* qb = q + bh * SEQ * DH;
  const unsigned short* kb = k + bh * SEQ * DH;
  const unsigned short* vb = vT + bh * DH * SEQ;

  bf16x8 aq[4];
#pragma unroll
  for (int ks = 0; ks < 4; ++ks)
    aq[ks] = *(const bf16x8*)(qb + (r0 + fr) * DH + ks * 32 + fk);

  const int ntile = row0 / 32 + 2;
  const int wmax = r0 + 15;

  float rs[4] = {0.f, 0.f, 0.f, 0.f};

  // ---- pass A: row sums ----
  for (int nt = 0; nt < ntile; ++nt) {
    const int c0 = nt * 32;
    __syncthreads();
#pragma unroll
    for (int j = 0; j < 2; ++j) {
      int f = j * 256 + tid;
      int r = f >> 4, c = (f & 15) * 8;
      *(bf16x8*)&Kt[r][c] = *(const bf16x8*)(kb + (c0 + r) * DH + c);
    }
    __syncthreads();
    if (c0 <= wmax) {
#pragma unroll
      for (int half = 0; half < 2; ++half) {
        f32x4 s = {0.f, 0.f, 0.f, 0.f};
#pragma unroll
        for (int ks = 0; ks < 4; ++ks) {
          bf16x8 bk = *(const bf16x8*)&Kt[half * 16 + fr][ks * 32 + fk];
          s = MFMA(aq[ks], bk, s);
        }
        int col = c0 + half * 16 + fr;
#pragma unroll
        for (int r = 0; r < 4; ++r) {
          int row = r0 + fq * 4 + r;
          if (col <= row) rs[r] += __expf(s[r] * SCALE);
        }
      }
    }
  }

#pragma unroll
  for (int r = 0; r < 4; ++r)
#pragma unroll
    for (int msk = 1; msk < 16; msk <<= 1)
      rs[r] += __shfl_xor(rs[r], msk, 64);

  float inv[4];
#pragma unroll
  for (int r = 0; r < 4; ++r) inv[r] = 1.0f / rs[r];

  f32x4 pv[8];
  {
    f32x4 zero4 = {0.f, 0.f, 0.f, 0.f};
#pragma unroll
    for (int i = 0; i < 8; ++i) pv[i] = zero4;
  }

  // ---- pass B: normalized attn write (f32) + PV ----
  for (int nt = 0; nt < ntile; ++nt) {
    const int c0 = nt * 32;
    __syncthreads();
#pragma unroll
    for (int j = 0; j < 2; ++j) {
      int f = j * 256 + tid;
      int r = f >> 4, c = (f & 15) * 8;
      *(bf16x8*)&Kt[r][c] = *(const bf16x8*)(kb + (c0 + r) * DH + c);
      int rv = f >> 2, cv = (f & 3) * 8;
      *(bf16x8*)&Vt[rv][cv] = *(const bf16x8*)(vb + rv * SEQ + c0 + cv);
    }
    __syncthreads();
    if (c0 <= wmax) {
#pragma unroll
      for (int half = 0; half < 2; ++half) {
        f32x4 s = {0.f, 0.f, 0.f, 0.f};
#pragma unroll
        for (int ks = 0; ks < 4; ++ks) {
          bf16x8 bk = *(const bf16x8*)&Kt[half * 16 + fr][ks * 32 + fk];
          s = MFMA(aq[ks], bk, s);
        }
        int col = c0 + half * 16 + fr;
#pragma unroll
        for (int r = 0; r < 4; ++r) {
          int row = r0 + fq * 4 + r;
          float p = (col <= row) ? __expf(s[r] * SCALE) * inv[r] : 0.f;
          attn[((size_t)bh * SEQ + row) * SEQ + col] = p;      // f32 output
          Esc[wave][fq * 4 + r][half * 16 + fr] = f2bf(p);     // PV fragment
        }
      }
      bf16x8 ae = *(const bf16x8*)&Esc[wave][fr][fk];
#pragma unroll
      for (int ni = 0; ni < 8; ++ni) {
        bf16x8 bv = *(const bf16x8*)&Vt[ni * 16 + fr][fk];
        pv[ni] = MFMA(ae, bv, pv[ni]);
      }
    }
  }

#pragma unroll
  for (int ni = 0; ni < 8; ++ni)
#pragma unroll
    for (int r = 0; r < 4; ++r) {
      int row = r0 + fq * 4 + r;
      int dh = ni * 16 + fr;
      heads[(bi * SEQ + row) * DIM + hh * DH + dh] = f2bf(pv[ni][r]);
    }

  // ---- tail: zero the untouched upper-triangle region for this wave ----
  // waves 0/1 wrote cols [0, row0+32); waves 2/3 wrote cols [0, row0+64)
  {
    const int zstart = row0 + ((wave >= 2) ? 64 : 32);
    f32x4 z4 = {0.f, 0.f, 0.f, 0.f};
#pragma unroll
    for (int rr = 0; rr < 4; ++rr) {
      int row = r0 + rr * 4 + fq;
      float* dst = attn + ((size_t)bh * SEQ + row) * SEQ;
      for (int c = zstart + fr * 4; c < SEQ; c += 64)
        *(f32x4*)(dst + c) = z4;
    }
  }
}

// ---------------------------------------------------------------------------
// K3: out = heads @ w_out^T  (M=4096, N=1024, K=1024), f32 output
// ---------------------------------------------------------------------------
__global__ __launch_bounds__(256) void k_outproj(
    const unsigned short* __restrict__ heads, const float* __restrict__ wout,
    float* __restrict__ out)
{
  __shared__ __align__(16) unsigned short As[128][40];
  __shared__ __align__(16) unsigned short Bs[128][40];
  const int tid = threadIdx.x;
  const int wave = tid >> 6, lane = tid & 63;
  const int fr = lane & 15, fq = lane >> 4;
  const int fk = fq * 8;
  const int wr = (wave >> 1) * 64, wc = (wave & 1) * 64;
  const int m0 = blockIdx.x * 128, n0 = blockIdx.y * 128;

  f32x4 zero4 = {0.f, 0.f, 0.f, 0.f};
  f32x4 acc[4][4];
  for (int i = 0; i < 4; ++i)
    for (int j = 0; j < 4; ++j) acc[i][j] = zero4;

  for (int kt = 0; kt < 32; ++kt) {
    const int k0 = kt * 32;
    __syncthreads();
#pragma unroll
    for (int j = 0; j < 2; ++j) { // A tile: 128x32 bf16
      int f = j * 256 + tid;
      int row = f >> 2, c = (f & 3) * 8;
      *(bf16x8*)&As[row][c] = *(const bf16x8*)(heads + (m0 + row) * 1024 + k0 + c);
    }
#pragma unroll
    for (int j = 0; j < 4; ++j) { // B tile: 128x32 f32 -> bf16
      int f = j * 256 + tid;
      int row = f >> 3, c4 = (f & 7) * 4;
      f32x4 vb = *(const f32x4*)(wout + (n0 + row) * 1024 + k0 + c4);
      bf16x4 hb;
#pragma unroll
      for (int e = 0; e < 4; ++e) hb[e] = (short)f2bf(vb[e]);
      *(bf16x4*)&Bs[row][c4] = hb;
    }
    __syncthreads();
    bf16x8 af[4], bfr[4];
#pragma unroll
    for (int mi = 0; mi < 4; ++mi) af[mi] = *(const bf16x8*)&As[wr + mi * 16 + fr][fk];
#pragma unroll
    for (int ni = 0; ni < 4; ++ni) bfr[ni] = *(const bf16x8*)&Bs[wc + ni * 16 + fr][fk];
#pragma unroll
    for (int mi = 0; mi < 4; ++mi)
#pragma unroll
      for (int ni = 0; ni < 4; ++ni)
        acc[mi][ni] = MFMA(af[mi], bfr[ni], acc[mi][ni]);
  }

#pragma unroll
  for (int mi = 0; mi < 4; ++mi)
#pragma unroll
    for (int ni = 0; ni < 4; ++ni)
#pragma unroll
      for (int r = 0; r < 4; ++r) {
        int m = m0 + wr + mi * 16 + fq * 4 + r;
        int n = n0 + wc + ni * 16 + fr;
        out[m * 1024 + n] = acc[mi][ni][r];
      }
}

extern "C" void kernel_launch(void* const* d_in, const int* in_sizes, int n_in,
                              void* d_out, int out_size, void* d_ws, size_t ws_size,
                              hipStream_t stream)
{
  const float* x    = (const float*)d_in[0];
  const float* wqkv = (const float*)d_in[1];
  const float* wout = (const float*)d_in[2];
  const float* cosT = (const float*)d_in[3];
  const float* sinT = (const float*)d_in[4];

  float* out  = (float*)d_out;
  float* attn = out + 4194304; // B*T*DIM f32 elements, then attn f32
  unsigned short* ws   = (unsigned short*)d_ws;
  unsigned short* q     = ws;             // (B,H,T,DH) bf16
  unsigned short* kk    = ws + 4194304;   // (B,H,T,DH) bf16
  unsigned short* vT    = ws + 8388608;   // (B,H,DH,T) bf16
  unsigned short* heads = ws + 12582912;  // (B,T,DIM) bf16

  k_qkv_rope<<<dim3(32, 24), 256, 0, stream>>>(x, wqkv, cosT, sinT, q, kk, vT);
  k_attn<<<dim3(32, 8, 2), 256, 0, stream>>>(q, kk, vT, attn, heads);
  k_outproj<<<dim3(32, 8), 256, 0, stream>>>(heads, wout, out);
}

// Round 4
// 219.704 us; speedup vs baseline: 1.2847x; 1.1005x over previous
//
#include <hip/hip_runtime.h>

typedef __attribute__((ext_vector_type(8))) short bf16x8;
typedef __attribute__((ext_vector_type(4))) short bf16x4;
typedef __attribute__((ext_vector_type(4))) float f32x4;

#define MFMA(a, b, c) __builtin_amdgcn_mfma_f32_16x16x32_bf16((a), (b), (c), 0, 0, 0)

__device__ __forceinline__ unsigned short f2bf(float f) {
  unsigned int x = __float_as_uint(f);
  return (unsigned short)((x + 0x7fffu + ((x >> 16) & 1u)) >> 16);
}
// packed f32 pair -> 2xbf16 in one VALU op (no builtin on gfx950; T12 recipe)
__device__ __forceinline__ unsigned int cvtpk(float lo, float hi) {
  unsigned int r;
  asm("v_cvt_pk_bf16_f32 %0, %1, %2" : "=v"(r) : "v"(lo), "v"(hi));
  return r;
}

constexpr int SEQ = 2048;
constexpr int NH = 8;
constexpr int DH = 128;
constexpr int DIM = 1024;
constexpr float SCALE = 0.08838834764831845f; // 1/sqrt(128)

// ---------------------------------------------------------------------------
// K1: qkv = x @ qkv_proj^T  (M=4096, N=3072, K=1024), fused RoPE epilogue.
// Staging converts f32->bf16 via v_cvt_pk_bf16_f32 (2 elems/instr).
// ---------------------------------------------------------------------------
__global__ __launch_bounds__(256) void k_qkv_rope(
    const float* __restrict__ x, const float* __restrict__ wqkv,
    const float* __restrict__ cosT, const float* __restrict__ sinT,
    unsigned short* __restrict__ q, unsigned short* __restrict__ k,
    unsigned short* __restrict__ vT)
{
  __shared__ __align__(16) unsigned short As[128][40]; // pitch 80B: 2-way max on b128 (free)
  __shared__ __align__(16) unsigned short Bs[128][40];
  const int tid = threadIdx.x;
  const int wave = tid >> 6, lane = tid & 63;
  const int fr = lane & 15, fq = lane >> 4;
  const int fk = fq * 8;
  const int wr = (wave >> 1) * 64, wc = (wave & 1) * 64;
  const int m0 = blockIdx.x * 128, n0 = blockIdx.y * 128;

  f32x4 zero4 = {0.f, 0.f, 0.f, 0.f};
  f32x4 acc[4][4];
  for (int i = 0; i < 4; ++i)
    for (int j = 0; j < 4; ++j) acc[i][j] = zero4;

  for (int kt = 0; kt < 32; ++kt) {
    const int k0 = kt * 32;
    __syncthreads();
#pragma unroll
    for (int j = 0; j < 4; ++j) {
      int f = j * 256 + tid;
      int row = f >> 3, c4 = (f & 7) * 4;
      f32x4 va = *(const f32x4*)(x + (m0 + row) * 1024 + k0 + c4);
      f32x4 vb = *(const f32x4*)(wqkv + (n0 + row) * 1024 + k0 + c4);
      uint2 ua, ub;
      ua.x = cvtpk(va[0], va[1]); ua.y = cvtpk(va[2], va[3]);
      ub.x = cvtpk(vb[0], vb[1]); ub.y = cvtpk(vb[2], vb[3]);
      *(uint2*)&As[row][c4] = ua;
      *(uint2*)&Bs[row][c4] = ub;
    }
    __syncthreads();
    bf16x8 af[4], bfr[4];
#pragma unroll
    for (int mi = 0; mi < 4; ++mi) af[mi] = *(const bf16x8*)&As[wr + mi * 16 + fr][fk];
#pragma unroll
    for (int ni = 0; ni < 4; ++ni) bfr[ni] = *(const bf16x8*)&Bs[wc + ni * 16 + fr][fk];
#pragma unroll
    for (int mi = 0; mi < 4; ++mi)
#pragma unroll
      for (int ni = 0; ni < 4; ++ni)
        acc[mi][ni] = MFMA(af[mi], bfr[ni], acc[mi][ni]);
  }

  // epilogue: D layout col=lane&15, row=(lane>>4)*4+r. Feature pairs (2i,2i+1)
  // sit in lanes (l, l^1) at the same row -> RoPE via shfl_xor(1).
#pragma unroll
  for (int mi = 0; mi < 4; ++mi)
#pragma unroll
    for (int ni = 0; ni < 4; ++ni)
#pragma unroll
      for (int r = 0; r < 4; ++r) {
        float val = acc[mi][ni][r];
        float other = __shfl_xor(val, 1, 64);
        int m = m0 + wr + mi * 16 + fq * 4 + r;
        int n = n0 + wc + ni * 16 + fr;
        int a = n >> 10, feat = n & 1023;
        int hh = feat >> 7, dh = feat & 127;
        int bi = m >> 11, t = m & 2047;
        if (a == 2) {
          vT[((bi * NH + hh) * DH + dh) * SEQ + t] = f2bf(val);
        } else {
          float c = cosT[t * 64 + (dh >> 1)];
          float s = sinT[t * 64 + (dh >> 1)];
          float o = ((dh & 1) == 0) ? (val * c - other * s) : (other * s + val * c);
          unsigned short* dst = (a == 0) ? q : k;
          dst[((bi * NH + hh) * SEQ + t) * DH + dh] = f2bf(o);
        }
      }
}

// ---------------------------------------------------------------------------
// K2: causal attention per (b, head, 64-row tile). 64-col K/V tiles (half the
// barriers of the 32-col version). Pass A: rowsums of exp. Pass B: recompute,
// write normalized f32 attn + bf16 P (LDS transpose) + PV. Tail: zero-fill
// cols [row0+64, 2048).
// ---------------------------------------------------------------------------
__global__ __launch_bounds__(256) void k_attn(
    const unsigned short* __restrict__ q, const unsigned short* __restrict__ k,
    const unsigned short* __restrict__ vT,
    float* __restrict__ attn, unsigned short* __restrict__ heads)
{
  __shared__ __align__(16) unsigned short Kt[64][140];   // pitch 140: 6r bank walk
  __shared__ __align__(16) unsigned short Vt[128][76];
  __shared__ __align__(16) unsigned short Esc[4][16][76];

  const int tid = threadIdx.x;
  const int wave = tid >> 6, lane = tid & 63;
  const int fr = lane & 15, fq = lane >> 4;
  const int fk = fq * 8;
  const int rt = (blockIdx.z == 0) ? (int)blockIdx.x : (31 - (int)blockIdx.x);
  const int row0 = rt * 64;
  const int hh = blockIdx.y, bi = blockIdx.z;
  const int bh = bi * NH + hh;
  const int r0 = row0 + wave * 16;

  const unsigned short* qb = q + bh * SEQ * DH;
  const unsigned short* kb = k + bh * SEQ * DH;
  const unsigned short* vb = vT + bh * DH * SEQ;

  bf16x8 aq[4];
#pragma unroll
  for (int ks = 0; ks < 4; ++ks)
    aq[ks] = *(const bf16x8*)(qb + (r0 + fr) * DH + ks * 32 + fk);

  const int wmax = r0 + 15;
  float rs[4] = {0.f, 0.f, 0.f, 0.f};

  // ---- pass A: row sums (tiles 0..rt, 64 cols each) ----
  for (int nt = 0; nt <= rt; ++nt) {
    const int c0 = nt * 64;
    __syncthreads();
#pragma unroll
    for (int j = 0; j < 4; ++j) {
      int f = j * 256 + tid;
      int r = f >> 4, c = (f & 15) * 8;
      *(bf16x8*)&Kt[r][c] = *(const bf16x8*)(kb + (c0 + r) * DH + c);
    }
    __syncthreads();
#pragma unroll
    for (int half = 0; half < 4; ++half) {
      int ch = c0 + half * 16;
      if (ch <= wmax) {
        f32x4 s = {0.f, 0.f, 0.f, 0.f};
#pragma unroll
        for (int ks = 0; ks < 4; ++ks) {
          bf16x8 bk = *(const bf16x8*)&Kt[half * 16 + fr][ks * 32 + fk];
          s = MFMA(aq[ks], bk, s);
        }
        int col = ch + fr;
#pragma unroll
        for (int r = 0; r < 4; ++r) {
          int row = r0 + fq * 4 + r;
          if (col <= row) rs[r] += __expf(s[r] * SCALE);
        }
      }
    }
  }

#pragma unroll
  for (int r = 0; r < 4; ++r)
#pragma unroll
    for (int msk = 1; msk < 16; msk <<= 1)
      rs[r] += __shfl_xor(rs[r], msk, 64);

  float inv[4];
#pragma unroll
  for (int r = 0; r < 4; ++r) inv[r] = 1.0f / rs[r];

  f32x4 pv[8];
  {
    f32x4 zero4 = {0.f, 0.f, 0.f, 0.f};
#pragma unroll
    for (int i = 0; i < 8; ++i) pv[i] = zero4;
  }

  // ---- pass B: normalized attn write (f32) + PV ----
  for (int nt = 0; nt <= rt; ++nt) {
    const int c0 = nt * 64;
    __syncthreads();
#pragma unroll
    for (int j = 0; j < 4; ++j) {
      int f = j * 256 + tid;
      int r = f >> 4, c = (f & 15) * 8;
      *(bf16x8*)&Kt[r][c] = *(const bf16x8*)(kb + (c0 + r) * DH + c);
      int rv = f >> 3, cv = (f & 7) * 8;
      *(bf16x8*)&Vt[rv][cv] = *(const bf16x8*)(vb + rv * SEQ + c0 + cv);
    }
    __syncthreads();
#pragma unroll
    for (int half = 0; half < 4; ++half) {
      int ch = c0 + half * 16;
      bool live = (ch <= wmax);
      f32x4 s = {0.f, 0.f, 0.f, 0.f};
      if (live) {
#pragma unroll
        for (int ks = 0; ks < 4; ++ks) {
          bf16x8 bk = *(const bf16x8*)&Kt[half * 16 + fr][ks * 32 + fk];
          s = MFMA(aq[ks], bk, s);
        }
      }
      int col = ch + fr;
#pragma unroll
      for (int r = 0; r < 4; ++r) {
        int row = r0 + fq * 4 + r;
        float p = (live && col <= row) ? __expf(s[r] * SCALE) * inv[r] : 0.f;
        attn[((size_t)bh * SEQ + row) * SEQ + col] = p;
        Esc[wave][fq * 4 + r][half * 16 + fr] = f2bf(p);
      }
    }
    // per-wave transpose readback (no barrier needed; same-wave LDS)
    bf16x8 ae0 = *(const bf16x8*)&Esc[wave][fr][fk];
    bf16x8 ae1 = *(const bf16x8*)&Esc[wave][fr][32 + fk];
#pragma unroll
    for (int ni = 0; ni < 8; ++ni) {
      bf16x8 bv0 = *(const bf16x8*)&Vt[ni * 16 + fr][fk];
      bf16x8 bv1 = *(const bf16x8*)&Vt[ni * 16 + fr][32 + fk];
      pv[ni] = MFMA(ae0, bv0, pv[ni]);
      pv[ni] = MFMA(ae1, bv1, pv[ni]);
    }
  }

#pragma unroll
  for (int ni = 0; ni < 8; ++ni)
#pragma unroll
    for (int r = 0; r < 4; ++r) {
      int row = r0 + fq * 4 + r;
      int dh = ni * 16 + fr;
      heads[(bi * SEQ + row) * DIM + hh * DH + dh] = f2bf(pv[ni][r]);
    }

  // ---- tail: zero cols [row0+64, 2048) for this wave's 16 rows ----
  {
    const int zstart = row0 + 64;
    f32x4 z4 = {0.f, 0.f, 0.f, 0.f};
#pragma unroll
    for (int rr = 0; rr < 4; ++rr) {
      int row = r0 + rr * 4 + fq;
      float* dst = attn + ((size_t)bh * SEQ + row) * SEQ;
      for (int c = zstart + fr * 4; c < SEQ; c += 64)
        *(f32x4*)(dst + c) = z4;
    }
  }
}

// ---------------------------------------------------------------------------
// K3: out = heads @ w_out^T  (M=4096, N=1024, K=1024), f32 output
// ---------------------------------------------------------------------------
__global__ __launch_bounds__(256) void k_outproj(
    const unsigned short* __restrict__ heads, const float* __restrict__ wout,
    float* __restrict__ out)
{
  __shared__ __align__(16) unsigned short As[128][40];
  __shared__ __align__(16) unsigned short Bs[128][40];
  const int tid = threadIdx.x;
  const int wave = tid >> 6, lane = tid & 63;
  const int fr = lane & 15, fq = lane >> 4;
  const int fk = fq * 8;
  const int wr = (wave >> 1) * 64, wc = (wave & 1) * 64;
  const int m0 = blockIdx.x * 128, n0 = blockIdx.y * 128;

  f32x4 zero4 = {0.f, 0.f, 0.f, 0.f};
  f32x4 acc[4][4];
  for (int i = 0; i < 4; ++i)
    for (int j = 0; j < 4; ++j) acc[i][j] = zero4;

  for (int kt = 0; kt < 32; ++kt) {
    const int k0 = kt * 32;
    __syncthreads();
#pragma unroll
    for (int j = 0; j < 2; ++j) { // A tile: 128x32 bf16
      int f = j * 256 + tid;
      int row = f >> 2, c = (f & 3) * 8;
      *(bf16x8*)&As[row][c] = *(const bf16x8*)(heads + (m0 + row) * 1024 + k0 + c);
    }
#pragma unroll
    for (int j = 0; j < 4; ++j) { // B tile: 128x32 f32 -> bf16 via cvt_pk
      int f = j * 256 + tid;
      int row = f >> 3, c4 = (f & 7) * 4;
      f32x4 vb = *(const f32x4*)(wout + (n0 + row) * 1024 + k0 + c4);
      uint2 ub;
      ub.x = cvtpk(vb[0], vb[1]); ub.y = cvtpk(vb[2], vb[3]);
      *(uint2*)&Bs[row][c4] = ub;
    }
    __syncthreads();
    bf16x8 af[4], bfr[4];
#pragma unroll
    for (int mi = 0; mi < 4; ++mi) af[mi] = *(const bf16x8*)&As[wr + mi * 16 + fr][fk];
#pragma unroll
    for (int ni = 0; ni < 4; ++ni) bfr[ni] = *(const bf16x8*)&Bs[wc + ni * 16 + fr][fk];
#pragma unroll
    for (int mi = 0; mi < 4; ++mi)
#pragma unroll
      for (int ni = 0; ni < 4; ++ni)
        acc[mi][ni] = MFMA(af[mi], bfr[ni], acc[mi][ni]);
  }

#pragma unroll
  for (int mi = 0; mi < 4; ++mi)
#pragma unroll
    for (int ni = 0; ni < 4; ++ni)
#pragma unroll
      for (int r = 0; r < 4; ++r) {
        int m = m0 + wr + mi * 16 + fq * 4 + r;
        int n = n0 + wc + ni * 16 + fr;
        out[m * 1024 + n] = acc[mi][ni][r];
      }
}

extern "C" void kernel_launch(void* const* d_in, const int* in_sizes, int n_in,
                              void* d_out, int out_size, void* d_ws, size_t ws_size,
                              hipStream_t stream)
{
  const float* x    = (const float*)d_in[0];
  const float* wqkv = (const float*)d_in[1];
  const float* wout = (const float*)d_in[2];
  const float* cosT = (const float*)d_in[3];
  const float* sinT = (const float*)d_in[4];

  float* out  = (float*)d_out;
  float* attn = out + 4194304; // B*T*DIM f32 elements, then attn f32
  unsigned short* ws   = (unsigned short*)d_ws;
  unsigned short* q     = ws;             // (B,H,T,DH) bf16
  unsigned short* kk    = ws + 4194304;   // (B,H,T,DH) bf16
  unsigned short* vT    = ws + 8388608;   // (B,H,DH,T) bf16
  unsigned short* heads = ws + 12582912;  // (B,T,DIM) bf16

  k_qkv_rope<<<dim3(32, 24), 256, 0, stream>>>(x, wqkv, cosT, sinT, q, kk, vT);
  k_attn<<<dim3(32, 8, 2), 256, 0, stream>>>(q, kk, vT, attn, heads);
  k_outproj<<<dim3(32, 8), 256, 0, stream>>>(heads, wout, out);
}